// Round 1
// baseline (1225.713 us; speedup 1.0000x reference)
//
#include <hip/hip_runtime.h>
#include <stdint.h>

#define NEGF (-1.0e8f)

// ---------------------------------------------------------------------------
// K1: T[22][512] = W_embed @ W_proj + b_proj
// ---------------------------------------------------------------------------
__global__ void k_T(const float* __restrict__ We, const float* __restrict__ Wp,
                    const float* __restrict__ bp, float* __restrict__ T) {
  int a = blockIdx.x, c = threadIdx.x;
  __shared__ float e[512];
  e[c] = We[a * 512 + c];
  __syncthreads();
  float acc = bp[c];
#pragma unroll 8
  for (int k = 0; k < 512; ++k) acc = fmaf(e[k], Wp[k * 512 + c], acc);
  T[a * 512 + c] = acc;
}

// ---------------------------------------------------------------------------
// K2: G[22][22] = T T^T ; u[a]=dot(T[a],Wg[0:512]) ; v[a]=dot(T[a],Wg[512:])
// ---------------------------------------------------------------------------
__global__ void k_G(const float* __restrict__ T, const float* __restrict__ Wg,
                    float* __restrict__ G, float* __restrict__ u, float* __restrict__ v) {
  __shared__ float Ts[22 * 516];  // stride 516 to break bank aliasing
  for (int k = threadIdx.x; k < 22 * 512; k += 512) {
    int a = k >> 9, c = k & 511;
    Ts[a * 516 + c] = T[k];
  }
  __syncthreads();
  for (int idx = threadIdx.x; idx < 528; idx += 512) {
    float s = 0.f;
    if (idx < 484) {
      int a = idx / 22, a2 = idx - 22 * a;
      const float* pa = &Ts[a * 516];
      const float* pb = &Ts[a2 * 516];
      for (int c = 0; c < 512; ++c) s = fmaf(pa[c], pb[c], s);
      G[idx] = s;
    } else if (idx < 506) {
      int a = idx - 484;
      const float* pa = &Ts[a * 516];
      for (int c = 0; c < 512; ++c) s = fmaf(pa[c], Wg[c], s);
      u[a] = s;
    } else {
      int a = idx - 506;
      const float* pa = &Ts[a * 516];
      for (int c = 0; c < 512; ++c) s = fmaf(pa[c], Wg[512 + c], s);
      v[a] = s;
    }
  }
}

// ---------------------------------------------------------------------------
// K3: A[b] = (sum_i u[x[b,i]] + sum_j v[y[b,j]]) / 512 + b_gap
// ---------------------------------------------------------------------------
__global__ void k_A(const int* __restrict__ x, const int* __restrict__ y,
                    const float* __restrict__ u, const float* __restrict__ v,
                    const float* __restrict__ bg, float* __restrict__ A) {
  int b = blockIdx.x, t = threadIdx.x;
  const int* xb = x + b * 512;
  const int* yb = y + b * 512;
  float s = u[xb[t]] + u[xb[t + 256]] + v[yb[t]] + v[yb[t + 256]];
  for (int o = 32; o > 0; o >>= 1) s += __shfl_down(s, o, 64);
  __shared__ float w[4];
  if ((t & 63) == 0) w[t >> 6] = s;
  __syncthreads();
  if (t == 0) A[b] = (w[0] + w[1] + w[2] + w[3]) * (1.0f / 512.0f) + bg[0];
}

// ---------------------------------------------------------------------------
// K4: per-batch NW forward (store packed softmax weights into d_out) then
//     backward (read weights, overwrite d_out with gradient E).
//     1 block = 1 batch, 256 threads, thread owns rows i1=2t+1, i2=2t+2.
// ---------------------------------------------------------------------------
__global__ __launch_bounds__(256) void k_nw(const int* __restrict__ x, const int* __restrict__ y,
                                            const float* __restrict__ G,
                                            const float* __restrict__ Aarr,
                                            float* __restrict__ out) {
  const int b = blockIdx.x, tid = threadIdx.x;
  __shared__ int xs[512], ys[512];
  __shared__ float Gl[484];
  __shared__ float V[3][516];
  __shared__ float E[4][516];

  const int* xb = x + b * 512;
  const int* yb = y + b * 512;
  xs[tid] = xb[tid];
  xs[tid + 256] = xb[tid + 256];
  ys[tid] = yb[tid];
  ys[tid + 256] = yb[tid + 256];
  for (int k = tid; k < 484; k += 256) Gl[k] = G[k];
  for (int k = tid; k < 516; k += 256) {
    V[0][k] = NEGF; V[1][k] = NEGF; V[2][k] = NEGF;
    E[0][k] = 0.f; E[1][k] = 0.f; E[2][k] = 0.f; E[3][k] = 0.f;
  }
  const float A = Aarr[b];
  __syncthreads();
  if (tid == 0) V[0][0] = 0.0f;  // V[0,0]=0 ; covered by first loop barrier

  const int i1 = 2 * tid + 1, i2 = i1 + 1;
  const int xr1 = xs[i1 - 1] * 22, xr2 = xs[i2 - 1] * 22;
  uint32_t* __restrict__ po = reinterpret_cast<uint32_t*>(out) + (size_t)b * (512 * 512);

  // ---------------- forward ----------------
  for (int d = 2; d <= 1024; ++d) {
    float* cur = V[d % 3];
    const float* pv = V[(d + 2) % 3];   // diagonal d-1
    const float* pv2 = V[(d + 1) % 3];  // diagonal d-2
    __syncthreads();
    {
      int j = d - i1;
      float vv = NEGF;
      if ((unsigned)(j - 1) < 512u) {
        float th = Gl[xr1 + ys[j - 1]];
        float dg = pv2[i1 - 1];
        float up = pv[i1 - 1] + A;
        float lf = pv[i1] + A;
        float m = fmaxf(fmaxf(dg, up), lf);
        float ed = __expf(dg - m), eu = __expf(up - m), el = __expf(lf - m);
        float s = ed + eu + el;
        vv = th + m + __logf(s);
        float sc = __builtin_amdgcn_rcpf(s) * 65535.0f;
        uint32_t pd = (uint32_t)(ed * sc + 0.5f);
        uint32_t pu = (uint32_t)(eu * sc + 0.5f);
        po[(i1 - 1) * 512 + (j - 1)] = pd | (pu << 16);
      }
      cur[i1] = vv;
    }
    {
      int j = d - i2;
      float vv = NEGF;
      if ((unsigned)(j - 1) < 512u) {
        float th = Gl[xr2 + ys[j - 1]];
        float dg = pv2[i2 - 1];
        float up = pv[i2 - 1] + A;
        float lf = pv[i2] + A;
        float m = fmaxf(fmaxf(dg, up), lf);
        float ed = __expf(dg - m), eu = __expf(up - m), el = __expf(lf - m);
        float s = ed + eu + el;
        vv = th + m + __logf(s);
        float sc = __builtin_amdgcn_rcpf(s) * 65535.0f;
        uint32_t pd = (uint32_t)(ed * sc + 0.5f);
        uint32_t pu = (uint32_t)(eu * sc + 0.5f);
        po[(i2 - 1) * 512 + (j - 1)] = pd | (pu << 16);
      }
      cur[i2] = vv;
    }
    if (tid == 0) cur[0] = NEGF;
  }

  // ---------------- backward ----------------
  __syncthreads();
  if (tid == 0) E[1024 & 3][512] = 1.0f;  // E[512,512] = 1 (diag 1024)
  const float inv16 = 1.0f / 65535.0f;

  for (int t = 1023; t >= 2; --t) {
    float* cur = E[t & 3];
    const float* e1 = E[(t + 1) & 3];
    const float* e2 = E[(t + 2) & 3];
    const float* e3 = E[(t + 3) & 3];
    __syncthreads();
    {
      int j = t - i1;
      float ev = 0.f;
      if ((unsigned)(j - 1) < 512u) {
        int oi = i1 - 1, oj = j - 1;
        bool dn = (i1 < 512), rt = (j < 512);
        uint32_t pk1 = po[(dn && rt) ? ((oi + 1) * 512 + (oj + 1)) : 0];
        uint32_t pk2 = po[dn ? ((oi + 1) * 512 + oj) : 0];
        uint32_t pk3 = po[rt ? (oi * 512 + (oj + 1)) : 0];
        float pd1 = (dn && rt) ? (float)(pk1 & 0xffffu) * inv16 : 0.f;
        float pu2 = dn ? (float)(pk2 >> 16) * inv16 : 0.f;
        float pl3 = rt ? (1.0f - (float)(pk3 & 0xffffu) * inv16 - (float)(pk3 >> 16) * inv16) : 0.f;
        ev = e2[i1 + 1] * pd1 + e1[i1 + 1] * pu2 + e1[i1] * pl3;
      }
      cur[i1] = ev;
    }
    {
      int j = t - i2;
      float ev = 0.f;
      if ((unsigned)(j - 1) < 512u) {
        int oi = i2 - 1, oj = j - 1;
        bool dn = (i2 < 512), rt = (j < 512);
        uint32_t pk1 = po[(dn && rt) ? ((oi + 1) * 512 + (oj + 1)) : 0];
        uint32_t pk2 = po[dn ? ((oi + 1) * 512 + oj) : 0];
        uint32_t pk3 = po[rt ? (oi * 512 + (oj + 1)) : 0];
        float pd1 = (dn && rt) ? (float)(pk1 & 0xffffu) * inv16 : 0.f;
        float pu2 = dn ? (float)(pk2 >> 16) * inv16 : 0.f;
        float pl3 = rt ? (1.0f - (float)(pk3 & 0xffffu) * inv16 - (float)(pk3 >> 16) * inv16) : 0.f;
        ev = e2[i2 + 1] * pd1 + e1[i2 + 1] * pu2 + e1[i2] * pl3;
      }
      cur[i2] = ev;
    }
    if (tid == 0) cur[0] = 0.f;

    // retire diagonal t+3 (its p-cells were last read at step t+1)
    int d3 = t + 3;
    if (d3 <= 1024) {
      int j3 = d3 - i1;
      if ((unsigned)(j3 - 1) < 512u) po[(i1 - 1) * 512 + (j3 - 1)] = __float_as_uint(e3[i1]);
      j3 = d3 - i2;
      if ((unsigned)(j3 - 1) < 512u) po[(i2 - 1) * 512 + (j3 - 1)] = __float_as_uint(e3[i2]);
    }
  }
  __syncthreads();
  // flush diagonals 2,3,4
  for (int d = 2; d <= 4; ++d) {
    const float* eb = E[d & 3];
    int j = d - i1;
    if ((unsigned)(j - 1) < 512u) po[(i1 - 1) * 512 + (j - 1)] = __float_as_uint(eb[i1]);
    j = d - i2;
    if ((unsigned)(j - 1) < 512u) po[(i2 - 1) * 512 + (j - 1)] = __float_as_uint(eb[i2]);
  }
}

// ---------------------------------------------------------------------------
extern "C" void kernel_launch(void* const* d_in, const int* in_sizes, int n_in,
                              void* d_out, int out_size, void* d_ws, size_t ws_size,
                              hipStream_t stream) {
  const int* x = (const int*)d_in[0];
  const int* y = (const int*)d_in[1];
  const float* We = (const float*)d_in[2];
  const float* Wp = (const float*)d_in[3];
  const float* bp = (const float*)d_in[4];
  const float* Wg = (const float*)d_in[5];
  const float* bg = (const float*)d_in[6];
  float* out = (float*)d_out;

  float* ws = (float*)d_ws;
  float* T = ws;              // 22*512 = 11264 floats
  float* G = ws + 11264;      // 484
  float* u = G + 484;         // 22
  float* v = u + 22;          // 22
  float* A = v + 22;          // 16

  k_T<<<22, 512, 0, stream>>>(We, Wp, bp, T);
  k_G<<<1, 512, 0, stream>>>(T, Wg, G, u, v);
  k_A<<<16, 256, 0, stream>>>(x, y, u, v, bg, A);
  k_nw<<<16, 256, 0, stream>>>(x, y, G, A, out);
}

// Round 2
// 1200.883 us; speedup vs baseline: 1.0207x; 1.0207x over previous
//
#include <hip/hip_runtime.h>
#include <stdint.h>

#define NEGF (-1.0e8f)
#define NCELL (512 * 512)

// offset of diagonal d (d in [2,1024]) in diag-major storage; lo(d)=max(1,d-512)
__device__ __forceinline__ int offd(int d) {
  return (d <= 513) ? (((d - 2) * (d - 1)) >> 1)
                    : (NCELL - (((1025 - d) * (1026 - d)) >> 1));
}

// ---------------------------------------------------------------------------
// K1: T[22][512] = W_embed @ W_proj + b_proj
// ---------------------------------------------------------------------------
__global__ void k_T(const float* __restrict__ We, const float* __restrict__ Wp,
                    const float* __restrict__ bp, float* __restrict__ T) {
  int a = blockIdx.x, c = threadIdx.x;
  __shared__ float e[512];
  e[c] = We[a * 512 + c];
  __syncthreads();
  float acc = bp[c];
#pragma unroll 8
  for (int k = 0; k < 512; ++k) acc = fmaf(e[k], Wp[k * 512 + c], acc);
  T[a * 512 + c] = acc;
}

// ---------------------------------------------------------------------------
// K2: G[22][22] = T T^T ; u[a]=dot(T[a],Wg[0:512]) ; v[a]=dot(T[a],Wg[512:])
// ---------------------------------------------------------------------------
__global__ void k_G(const float* __restrict__ T, const float* __restrict__ Wg,
                    float* __restrict__ G, float* __restrict__ u, float* __restrict__ v) {
  __shared__ float Ts[22 * 516];
  for (int k = threadIdx.x; k < 22 * 512; k += 512) {
    int a = k >> 9, c = k & 511;
    Ts[a * 516 + c] = T[k];
  }
  __syncthreads();
  for (int idx = threadIdx.x; idx < 528; idx += 512) {
    float s = 0.f;
    if (idx < 484) {
      int a = idx / 22, a2 = idx - 22 * a;
      const float* pa = &Ts[a * 516];
      const float* pb = &Ts[a2 * 516];
      for (int c = 0; c < 512; ++c) s = fmaf(pa[c], pb[c], s);
      G[idx] = s;
    } else if (idx < 506) {
      int a = idx - 484;
      const float* pa = &Ts[a * 516];
      for (int c = 0; c < 512; ++c) s = fmaf(pa[c], Wg[c], s);
      u[a] = s;
    } else {
      int a = idx - 506;
      const float* pa = &Ts[a * 516];
      for (int c = 0; c < 512; ++c) s = fmaf(pa[c], Wg[512 + c], s);
      v[a] = s;
    }
  }
}

// ---------------------------------------------------------------------------
// K3: A[b] = (sum_i u[x[b,i]] + sum_j v[y[b,j]]) / 512 + b_gap
// ---------------------------------------------------------------------------
__global__ void k_A(const int* __restrict__ x, const int* __restrict__ y,
                    const float* __restrict__ u, const float* __restrict__ v,
                    const float* __restrict__ bg, float* __restrict__ A) {
  int b = blockIdx.x, t = threadIdx.x;
  const int* xb = x + b * 512;
  const int* yb = y + b * 512;
  float s = u[xb[t]] + u[xb[t + 256]] + v[yb[t]] + v[yb[t + 256]];
  for (int o = 32; o > 0; o >>= 1) s += __shfl_down(s, o, 64);
  __shared__ float w[4];
  if ((t & 63) == 0) w[t >> 6] = s;
  __syncthreads();
  if (t == 0) A[b] = (w[0] + w[1] + w[2] + w[3]) * (1.0f / 512.0f) + bg[0];
}

// ---------------------------------------------------------------------------
// K4: per-batch NW forward (diag-major packed p -> d_out) then backward
//     (prefetched coalesced p loads, diag-major E -> ws).
//     1 block = 1 batch, 256 threads, thread owns rows i1=2t+1, i2=2t+2.
// ---------------------------------------------------------------------------
__global__ __launch_bounds__(256) void k_nw(const int* __restrict__ x, const int* __restrict__ y,
                                            const float* __restrict__ G,
                                            const float* __restrict__ Aarr,
                                            uint32_t* __restrict__ po,
                                            float* __restrict__ ews) {
  const int b = blockIdx.x, tid = threadIdx.x;
  __shared__ int xs[512], ys[512];
  __shared__ float Gl[484];
  __shared__ float V[3][516];
  __shared__ float Eb[3][516];

  const int* xb = x + b * 512;
  const int* yb = y + b * 512;
  xs[tid] = xb[tid]; xs[tid + 256] = xb[tid + 256];
  ys[tid] = yb[tid]; ys[tid + 256] = yb[tid + 256];
  for (int k = tid; k < 484; k += 256) Gl[k] = G[k];
  for (int k = tid; k < 3 * 516; k += 256) (&V[0][0])[k] = NEGF;
  const float A = Aarr[b];
  __syncthreads();
  if (tid == 0) V[0][0] = 0.0f;  // diag-0 buffer; read first after loop's barrier

  const int i1 = 2 * tid + 1, i2 = i1 + 1;
  const int xr1 = xs[i1 - 1] * 22, xr2 = xs[i2 - 1] * 22;
  po += (size_t)b * NCELL;
  ews += (size_t)b * NCELL;

  // ---------------- forward ----------------
  for (int d = 2; d <= 1024; ++d) {
    float* cur = V[d % 3];
    const float* pv = V[(d + 2) % 3];   // diag d-1
    const float* pv2 = V[(d + 1) % 3];  // diag d-2
    const int lo = (d - 512 > 1) ? d - 512 : 1;
    const int hi = (d - 1 < 512) ? d - 1 : 512;
    const int base = offd(d) - lo;
    __syncthreads();
    float vv1 = NEGF, vv2 = NEGF;
    if (i1 >= lo && i1 <= hi) {
      int j = d - i1;
      float th = Gl[xr1 + ys[j - 1]];
      float dg = pv2[i1 - 1];
      float up = pv[i1 - 1] + A;
      float lf = pv[i1] + A;
      float m = fmaxf(fmaxf(dg, up), lf);
      float ed = __expf(dg - m), eu = __expf(up - m), el = __expf(lf - m);
      float s = ed + eu + el;
      vv1 = th + m + __logf(s);
      float sc = __builtin_amdgcn_rcpf(s) * 65535.0f;
      uint32_t pd = (uint32_t)(ed * sc + 0.5f);
      uint32_t pu = (uint32_t)(eu * sc + 0.5f);
      po[base + i1] = pd | (pu << 16);
    }
    if (i2 >= lo && i2 <= hi) {
      int j = d - i2;
      float th = Gl[xr2 + ys[j - 1]];
      float dg = pv2[i2 - 1];
      float up = pv[i2 - 1] + A;
      float lf = pv[i2] + A;
      float m = fmaxf(fmaxf(dg, up), lf);
      float ed = __expf(dg - m), eu = __expf(up - m), el = __expf(lf - m);
      float s = ed + eu + el;
      vv2 = th + m + __logf(s);
      float sc = __builtin_amdgcn_rcpf(s) * 65535.0f;
      uint32_t pd = (uint32_t)(ed * sc + 0.5f);
      uint32_t pu = (uint32_t)(eu * sc + 0.5f);
      po[base + i2] = pd | (pu << 16);
    }
    cur[i1] = vv1;
    cur[i2] = vv2;
    if (tid == 0) cur[0] = NEGF;
  }

  // ---------------- backward ----------------
  __threadfence_block();  // p stores visible to this block's loads
  __syncthreads();
  for (int k = tid; k < 3 * 516; k += 256) (&Eb[0][0])[k] = 0.f;
  __syncthreads();
  if (tid == 0) {
    Eb[1024 % 3][512] = 1.0f;   // E[512,512]=1 (diag 1024)
    ews[NCELL - 1] = 1.0f;      // store it
  }

  const float inv16 = 1.0f / 65535.0f;
  uint32_t A1, A2, A3, A4, A5, B1, B2, B3, B4, B5;

  // issue the 5 p-loads for step t (cells i1,i2): k1a=p(i1+1,j1+1)@t+2,
  // k23=p(i2,j1)@t+1 (shared: pu of cell1 / pl-source of cell2),
  // k3a=p(i1,j1+1)@t+1, k1b=p(i2+1,j2+1)@t+2, k2b=p(i2+1,j2)@t+1.
  auto ISSUE = [&](int t, uint32_t& k1a, uint32_t& k23, uint32_t& k3a,
                   uint32_t& k1b, uint32_t& k2b) {
    const int d1 = t + 1;
    const int d2 = (t + 2 < 1024) ? t + 2 : 1024;
    const int b1 = offd(d1) - ((d1 - 512 > 1) ? d1 - 512 : 1);
    const int b2 = offd(d2) - ((d2 - 512 > 1) ? d2 - 512 : 1);
    int a;
    a = b2 + i1 + 1; if (a > NCELL - 1) a = NCELL - 1; k1a = po[a];
    a = b1 + i2;     if (a > NCELL - 1) a = NCELL - 1; k23 = po[a];
    a = b1 + i1;     if (a > NCELL - 1) a = NCELL - 1; k3a = po[a];
    a = b2 + i2 + 1; if (a > NCELL - 1) a = NCELL - 1; k1b = po[a];
    a = b1 + i2 + 1; if (a > NCELL - 1) a = NCELL - 1; k2b = po[a];
  };

  auto COMPUTE = [&](int t, uint32_t k1a, uint32_t k23, uint32_t k3a,
                     uint32_t k1b, uint32_t k2b) {
    float* cur = Eb[t % 3];
    const float* e1 = Eb[(t + 1) % 3];
    const float* e2 = Eb[(t + 2) % 3];
    const int lo = (t - 512 > 1) ? t - 512 : 1;
    const int hi = (t - 1 < 512) ? t - 1 : 512;
    const int baset = offd(t) - lo;
    float ev1 = 0.f, ev2 = 0.f;
    if (i1 >= lo && i1 <= hi) {
      const bool rt = (t - i1) < 512;  // i1<512 always -> dn true
      float pd = rt ? (float)(k1a & 0xffffu) * inv16 : 0.f;
      float pu = (float)(k23 >> 16) * inv16;
      float pl = rt ? (1.0f - (float)(k3a & 0xffffu) * inv16 - (float)(k3a >> 16) * inv16) : 0.f;
      ev1 = e2[i1 + 1] * pd + e1[i1 + 1] * pu + e1[i1] * pl;
      ews[baset + i1] = ev1;
    }
    if (i2 >= lo && i2 <= hi) {
      const bool dn = i2 < 512;
      const bool rt = (t - i2) < 512;
      float pd = (dn && rt) ? (float)(k1b & 0xffffu) * inv16 : 0.f;
      float pu = dn ? (float)(k2b >> 16) * inv16 : 0.f;
      float pl = rt ? (1.0f - (float)(k23 & 0xffffu) * inv16 - (float)(k23 >> 16) * inv16) : 0.f;
      ev2 = e2[i2 + 1] * pd + e1[i2 + 1] * pu + e1[i2] * pl;
      ews[baset + i2] = ev2;
    }
    cur[i1] = ev1;
    cur[i2] = ev2;
  };

  ISSUE(1023, A1, A2, A3, A4, A5);
  for (int t = 1023; t >= 3; t -= 2) {
    ISSUE(t - 1, B1, B2, B3, B4, B5);  // prefetch before barrier
    __syncthreads();
    COMPUTE(t, A1, A2, A3, A4, A5);
    if (t >= 5) ISSUE(t - 2, A1, A2, A3, A4, A5);
    __syncthreads();
    COMPUTE(t - 1, B1, B2, B3, B4, B5);
  }
}

// ---------------------------------------------------------------------------
// K5: transpose diag-major E (ws) -> row-major out. 64x64 cell tiles.
// ---------------------------------------------------------------------------
__global__ __launch_bounds__(256) void k_tr(const float* __restrict__ ews, float* __restrict__ out) {
  const int blk = blockIdx.x;
  const int b = blk >> 6, ti = (blk >> 3) & 7, tj = blk & 7;
  const float* src = ews + (size_t)b * NCELL;
  float* dst = out + (size_t)b * NCELL;
  __shared__ float tile[64][68];
  const int i0 = ti * 64, j0 = tj * 64;  // 0-based offsets; cells (i0+1.., j0+1..)
  const int t = threadIdx.x;
  const int sub = t >> 6, lane = t & 63;
  for (int k = sub; k < 127; k += 4) {
    const int d = i0 + j0 + 2 + k;
    const int ilo_t = max(i0 + 1, d - (j0 + 64));
    const int ihi_t = min(i0 + 64, d - (j0 + 1));
    const int i = ilo_t + lane;
    if (i <= ihi_t) {
      const int lo = (d - 512 > 1) ? d - 512 : 1;
      tile[i - 1 - i0][d - i - 1 - j0] = src[offd(d) - lo + i];
    }
  }
  __syncthreads();
  const int r = t >> 2, q = (t & 3) * 16;
  float4* drow = (float4*)&dst[(size_t)(i0 + r) * 512 + j0 + q];
  const float* srow = &tile[r][q];
  drow[0] = *(const float4*)&srow[0];
  drow[1] = *(const float4*)&srow[4];
  drow[2] = *(const float4*)&srow[8];
  drow[3] = *(const float4*)&srow[12];
}

// ---------------------------------------------------------------------------
extern "C" void kernel_launch(void* const* d_in, const int* in_sizes, int n_in,
                              void* d_out, int out_size, void* d_ws, size_t ws_size,
                              hipStream_t stream) {
  const int* x = (const int*)d_in[0];
  const int* y = (const int*)d_in[1];
  const float* We = (const float*)d_in[2];
  const float* Wp = (const float*)d_in[3];
  const float* bp = (const float*)d_in[4];
  const float* Wg = (const float*)d_in[5];
  const float* bg = (const float*)d_in[6];
  float* out = (float*)d_out;

  float* ws = (float*)d_ws;
  float* T = ws;              // 22*512 floats
  float* G = ws + 11264;      // 484
  float* u = G + 484;         // 22
  float* v = u + 22;          // 22
  float* A = v + 22;          // 16
  // diag-major E buffer: 16 MiB at +1 MiB
  float* ews = (float*)((char*)d_ws + (1 << 20));

  k_T<<<22, 512, 0, stream>>>(We, Wp, bp, T);
  k_G<<<1, 512, 0, stream>>>(T, Wg, G, u, v);
  k_A<<<16, 256, 0, stream>>>(x, y, u, v, bg, A);
  k_nw<<<16, 256, 0, stream>>>(x, y, G, A, (uint32_t*)d_out, ews);
  k_tr<<<16 * 64, 256, 0, stream>>>(ews, out);
}

// Round 4
// 1154.394 us; speedup vs baseline: 1.0618x; 1.0403x over previous
//
#include <hip/hip_runtime.h>
#include <stdint.h>

#define NEGF (-1.0e8f)
#define NCELL (512 * 512)
#define INVLN2 1.4426950408889634f

// raw barrier: LDS ordering only, never drains vmcnt (keeps global stores/loads in flight)
#define BAR() asm volatile("s_waitcnt lgkmcnt(0)\n\ts_barrier" ::: "memory")

__device__ __forceinline__ float exp2f_(float x) {
#if __has_builtin(__builtin_amdgcn_exp2f)
  return __builtin_amdgcn_exp2f(x);
#else
  return exp2f(x);
#endif
}
__device__ __forceinline__ float log2f_(float x) {
#if __has_builtin(__builtin_amdgcn_logf)
  return __builtin_amdgcn_logf(x);
#else
  return log2f(x);
#endif
}
__device__ __forceinline__ uint32_t pknorm16(float a, float b) {
#if __has_builtin(__builtin_amdgcn_cvt_pknorm_u16)
  typedef unsigned short u2v __attribute__((ext_vector_type(2)));
  union { u2v v; uint32_t u; } cv;
  cv.v = __builtin_amdgcn_cvt_pknorm_u16(a, b);
  return cv.u;
#else
  uint32_t pa = (uint32_t)(a * 65535.0f + 0.5f);
  uint32_t pb = (uint32_t)(b * 65535.0f + 0.5f);
  return pa | (pb << 16);
#endif
}

// offset of diagonal d (d in [2,1024]) in diag-major storage; lo(d)=max(1,d-512)
__device__ __forceinline__ int offd(int d) {
  return (d <= 513) ? (((d - 2) * (d - 1)) >> 1)
                    : (NCELL - (((1025 - d) * (1026 - d)) >> 1));
}

// ---------------------------------------------------------------------------
// K1: T[22][512] = W_embed @ W_proj + b_proj
// ---------------------------------------------------------------------------
__global__ void k_T(const float* __restrict__ We, const float* __restrict__ Wp,
                    const float* __restrict__ bp, float* __restrict__ T) {
  int a = blockIdx.x, c = threadIdx.x;
  __shared__ float e[512];
  e[c] = We[a * 512 + c];
  __syncthreads();
  float acc = bp[c];
#pragma unroll 8
  for (int k = 0; k < 512; ++k) acc = fmaf(e[k], Wp[k * 512 + c], acc);
  T[a * 512 + c] = acc;
}

// ---------------------------------------------------------------------------
// K2: G2[22][22] = (T T^T)/ln2 ; u[a]=dot(T[a],Wg[0:512]) ; v[a]=dot(T[a],Wg[512:])
// ---------------------------------------------------------------------------
__global__ void k_G(const float* __restrict__ T, const float* __restrict__ Wg,
                    float* __restrict__ G, float* __restrict__ u, float* __restrict__ v) {
  __shared__ float Ts[22 * 516];
  for (int k = threadIdx.x; k < 22 * 512; k += 512) {
    int a = k >> 9, c = k & 511;
    Ts[a * 516 + c] = T[k];
  }
  __syncthreads();
  for (int idx = threadIdx.x; idx < 528; idx += 512) {
    float s = 0.f;
    if (idx < 484) {
      int a = idx / 22, a2 = idx - 22 * a;
      const float* pa = &Ts[a * 516];
      const float* pb = &Ts[a2 * 516];
      for (int c = 0; c < 512; ++c) s = fmaf(pa[c], pb[c], s);
      G[idx] = s * INVLN2;  // base-2 domain
    } else if (idx < 506) {
      int a = idx - 484;
      const float* pa = &Ts[a * 516];
      for (int c = 0; c < 512; ++c) s = fmaf(pa[c], Wg[c], s);
      u[a] = s;
    } else {
      int a = idx - 506;
      const float* pa = &Ts[a * 516];
      for (int c = 0; c < 512; ++c) s = fmaf(pa[c], Wg[512 + c], s);
      v[a] = s;
    }
  }
}

// ---------------------------------------------------------------------------
// K3: A2[b] = ((sum_i u[x[b,i]] + sum_j v[y[b,j]])/512 + b_gap)/ln2
// ---------------------------------------------------------------------------
__global__ void k_A(const int* __restrict__ x, const int* __restrict__ y,
                    const float* __restrict__ u, const float* __restrict__ v,
                    const float* __restrict__ bg, float* __restrict__ A) {
  int b = blockIdx.x, t = threadIdx.x;
  const int* xb = x + b * 512;
  const int* yb = y + b * 512;
  float s = u[xb[t]] + u[xb[t + 256]] + v[yb[t]] + v[yb[t + 256]];
  for (int o = 32; o > 0; o >>= 1) s += __shfl_down(s, o, 64);
  __shared__ float w[4];
  if ((t & 63) == 0) w[t >> 6] = s;
  __syncthreads();
  if (t == 0) A[b] = ((w[0] + w[1] + w[2] + w[3]) * (1.0f / 512.0f) + bg[0]) * INVLN2;
}

// ---------------------------------------------------------------------------
// K4: per-batch NW forward (diag-major packed softmax weights -> d_out) then
//     backward (prefetched p loads, diag-major E -> ws). Raw barriers
//     (lgkm-only) keep global memory ops in flight across steps.
// ---------------------------------------------------------------------------
__global__ __launch_bounds__(256) void k_nw(const int* __restrict__ x, const int* __restrict__ y,
                                            const float* __restrict__ G,
                                            const float* __restrict__ Aarr,
                                            uint32_t* __restrict__ po,
                                            float* __restrict__ ews) {
  const int b = blockIdx.x, tid = threadIdx.x;
  __shared__ int xs[512], ys[512];
  __shared__ float Gl[484];
  __shared__ float V[3][516];
  __shared__ float Eb[3][516];

  const int* xb = x + b * 512;
  const int* yb = y + b * 512;
  xs[tid] = xb[tid]; xs[tid + 256] = xb[tid + 256];
  ys[tid] = yb[tid]; ys[tid + 256] = yb[tid + 256];
  for (int k = tid; k < 484; k += 256) Gl[k] = G[k];
  for (int k = tid; k < 3 * 516; k += 256) (&V[0][0])[k] = NEGF;
  const float A2 = Aarr[b];
  __syncthreads();
  if (tid == 0) V[0][0] = 0.0f;  // V[0,0]=0 ; visible after first BAR

  const int i1 = 2 * tid + 1, i2 = i1 + 1;
  const int xr1 = xs[i1 - 1] * 22, xr2 = xs[i2 - 1] * 22;
  po += (size_t)b * NCELL;
  ews += (size_t)b * NCELL;

  // prefetch theta for d=2 (ys-window rotation: ysa(d)=ys[d-i1-1], ysb=ysa(d-1))
  int ja = 1 - i1, jb = -i1;
  ja = ja < 0 ? 0 : ja; jb = jb < 0 ? 0 : jb;
  int ysa = ys[ja], ysb = ys[jb];
  float th1 = Gl[xr1 + ysa];
  float th2 = Gl[xr2 + ysb];

  // ---------------- forward ----------------
  for (int d = 2; d <= 1024; ++d) {
    float* cur = V[d % 3];
    const float* pv = V[(d + 2) % 3];   // diag d-1
    const float* pv2 = V[(d + 1) % 3];  // diag d-2
    const int lo = (d > 513) ? d - 512 : 1;
    const int hi = (d - 1 < 512) ? d - 1 : 512;
    const int base = offd(d) - lo;
    BAR();
    const float2 pvp = *(const float2*)&pv[i1 - 1];    // pv[i1-1], pv[i1]
    const float2 pv2p = *(const float2*)&pv2[i1 - 1];  // pv2[i1-1], pv2[i1]
    const float pvc = pv[i2];
    float vv1 = NEGF, vv2 = NEGF;
    if (i1 >= lo && i1 <= hi) {
      float dg = pv2p.x, up = pvp.x + A2, lf = pvp.y + A2;
      float m = fmaxf(fmaxf(dg, up), lf);
      float ed = exp2f_(dg - m), eu = exp2f_(up - m), el = exp2f_(lf - m);
      float s = ed + eu + el;
      vv1 = th1 + m + log2f_(s);
      float rs = __builtin_amdgcn_rcpf(s);
      po[base + i1] = pknorm16(ed * rs, eu * rs);
    }
    if (i2 >= lo && i2 <= hi) {
      float dg = pv2p.y, up = pvp.y + A2, lf = pvc + A2;
      float m = fmaxf(fmaxf(dg, up), lf);
      float ed = exp2f_(dg - m), eu = exp2f_(up - m), el = exp2f_(lf - m);
      float s = ed + eu + el;
      vv2 = th2 + m + log2f_(s);
      float rs = __builtin_amdgcn_rcpf(s);
      po[base + i2] = pknorm16(ed * rs, eu * rs);
    }
    *(float2*)&cur[i1] = make_float2(vv1, vv2);
    if (tid == 0) cur[0] = NEGF;
    // prefetch theta for step d+1 (consumed next iteration; latency hidden)
    int jn = d - i1;                       // ys index for next step's cell1
    jn = jn < 0 ? 0 : (jn > 511 ? 511 : jn);
    ysb = ysa;                             // rotate window
    ysa = ys[jn];
    th1 = Gl[xr1 + ysa];
    th2 = Gl[xr2 + ysb];
  }

  // ---------------- transition: drain stores once ----------------
  asm volatile("s_waitcnt vmcnt(0)" ::: "memory");
  __threadfence_block();
  __syncthreads();
  for (int k = tid; k < 3 * 516; k += 256) (&Eb[0][0])[k] = 0.f;
  __syncthreads();
  if (tid == 0) {
    Eb[1024 % 3][512] = 1.0f;  // E[512,512]=1 (diag 1024)
    ews[NCELL - 1] = 1.0f;
  }

  const float inv16 = 1.0f / 65535.0f;
  uint32_t A1, A2r, A3, A4, A5, B1, B2, B3, B4, B5;

  auto ISSUE = [&](int t, uint32_t& k1a, uint32_t& k23, uint32_t& k3a,
                   uint32_t& k1b, uint32_t& k2b) {
    const int d1 = t + 1;
    const int d2 = (t + 2 < 1024) ? t + 2 : 1024;
    const int b1 = offd(d1) - ((d1 > 513) ? d1 - 512 : 1);
    const int b2 = offd(d2) - ((d2 > 513) ? d2 - 512 : 1);
    int a;
    a = b2 + i1 + 1; if (a > NCELL - 1) a = NCELL - 1; k1a = po[a];
    a = b1 + i2;     if (a > NCELL - 1) a = NCELL - 1; k23 = po[a];
    a = b1 + i1;     if (a > NCELL - 1) a = NCELL - 1; k3a = po[a];
    a = b2 + i2 + 1; if (a > NCELL - 1) a = NCELL - 1; k1b = po[a];
    a = b1 + i2 + 1; if (a > NCELL - 1) a = NCELL - 1; k2b = po[a];
  };

  auto COMPUTE = [&](int t, uint32_t k1a, uint32_t k23, uint32_t k3a,
                     uint32_t k1b, uint32_t k2b) {
    float* cur = Eb[t % 3];
    const float* e1 = Eb[(t + 1) % 3];
    const float* e2 = Eb[(t + 2) % 3];
    const int lo = (t > 513) ? t - 512 : 1;
    const int hi = (t - 1 < 512) ? t - 1 : 512;
    const int baset = offd(t) - lo;
    const float2 e1p = *(const float2*)&e1[i1 + 1];  // e1[i1+1], e1[i1+2]
    const float e1a = e1[i1];
    const float2 e2p = *(const float2*)&e2[i1 + 1];  // e2[i1+1], e2[i1+2]
    float ev1 = 0.f, ev2 = 0.f;
    if (i1 >= lo && i1 <= hi) {
      const bool rt = (t - i1) < 512;
      float pd = rt ? (float)(k1a & 0xffffu) * inv16 : 0.f;
      float pu = (float)(k23 >> 16) * inv16;
      float pl = rt ? (1.0f - (float)(k3a & 0xffffu) * inv16 - (float)(k3a >> 16) * inv16) : 0.f;
      ev1 = e2p.x * pd + e1p.x * pu + e1a * pl;
      ews[baset + i1] = ev1;
    }
    if (i2 >= lo && i2 <= hi) {
      const bool dn = i2 < 512;
      const bool rt = (t - i2) < 512;
      float pd = (dn && rt) ? (float)(k1b & 0xffffu) * inv16 : 0.f;
      float pu = dn ? (float)(k2b >> 16) * inv16 : 0.f;
      float pl = rt ? (1.0f - (float)(k23 & 0xffffu) * inv16 - (float)(k23 >> 16) * inv16) : 0.f;
      ev2 = e2p.y * pd + e1p.y * pu + e1p.x * pl;
      ews[baset + i2] = ev2;
    }
    *(float2*)&cur[i1] = make_float2(ev1, ev2);
    if (tid == 0) cur[0] = 0.f;
  };

  ISSUE(1023, A1, A2r, A3, A4, A5);
  for (int t = 1023; t >= 3; t -= 2) {
    ISSUE(t - 1, B1, B2, B3, B4, B5);  // prefetch stays in flight across BAR
    BAR();
    COMPUTE(t, A1, A2r, A3, A4, A5);
    if (t >= 5) ISSUE(t - 2, A1, A2r, A3, A4, A5);
    BAR();
    COMPUTE(t - 1, B1, B2, B3, B4, B5);
  }
}

// ---------------------------------------------------------------------------
// K5: transpose diag-major E (ws) -> row-major out. 64x64 cell tiles.
// ---------------------------------------------------------------------------
__global__ __launch_bounds__(256) void k_tr(const float* __restrict__ ews, float* __restrict__ out) {
  const int blk = blockIdx.x;
  const int b = blk >> 6, ti = (blk >> 3) & 7, tj = blk & 7;
  const float* src = ews + (size_t)b * NCELL;
  float* dst = out + (size_t)b * NCELL;
  __shared__ float tile[64][68];
  const int i0 = ti * 64, j0 = tj * 64;
  const int t = threadIdx.x;
  const int sub = t >> 6, lane = t & 63;
  for (int k = sub; k < 127; k += 4) {
    const int d = i0 + j0 + 2 + k;
    const int ilo_t = max(i0 + 1, d - (j0 + 64));
    const int ihi_t = min(i0 + 64, d - (j0 + 1));
    const int i = ilo_t + lane;
    if (i <= ihi_t) {
      const int lo = (d > 513) ? d - 512 : 1;
      tile[i - 1 - i0][d - i - 1 - j0] = src[offd(d) - lo + i];
    }
  }
  __syncthreads();
  const int r = t >> 2, q = (t & 3) * 16;
  float4* drow = (float4*)&dst[(size_t)(i0 + r) * 512 + j0 + q];
  const float* srow = &tile[r][q];
  drow[0] = *(const float4*)&srow[0];
  drow[1] = *(const float4*)&srow[4];
  drow[2] = *(const float4*)&srow[8];
  drow[3] = *(const float4*)&srow[12];
}

// ---------------------------------------------------------------------------
extern "C" void kernel_launch(void* const* d_in, const int* in_sizes, int n_in,
                              void* d_out, int out_size, void* d_ws, size_t ws_size,
                              hipStream_t stream) {
  const int* x = (const int*)d_in[0];
  const int* y = (const int*)d_in[1];
  const float* We = (const float*)d_in[2];
  const float* Wp = (const float*)d_in[3];
  const float* bp = (const float*)d_in[4];
  const float* Wg = (const float*)d_in[5];
  const float* bg = (const float*)d_in[6];
  float* out = (float*)d_out;

  float* ws = (float*)d_ws;
  float* T = ws;              // 22*512 floats
  float* G = ws + 11264;      // 484
  float* u = G + 484;         // 22
  float* v = u + 22;          // 22
  float* A = v + 22;          // 16
  float* ews = (float*)((char*)d_ws + (1 << 20));  // 16 MiB diag-major E

  k_T<<<22, 512, 0, stream>>>(We, Wp, bp, T);
  k_G<<<1, 512, 0, stream>>>(T, Wg, G, u, v);
  k_A<<<16, 256, 0, stream>>>(x, y, u, v, bg, A);
  k_nw<<<16, 256, 0, stream>>>(x, y, G, A, (uint32_t*)d_out, ews);
  k_tr<<<16 * 64, 256, 0, stream>>>(ews, out);
}

// Round 5
// 747.281 us; speedup vs baseline: 1.6402x; 1.5448x over previous
//
#include <hip/hip_runtime.h>
#include <stdint.h>

#define NEGF (-1.0e8f)
#define NCELL (512 * 512)
#define INVLN2 1.4426950408889634f
#define KD 8  // diagonals per barrier interval

// raw barrier: LDS ordering only (never drains vmcnt)
#define BAR() asm volatile("s_waitcnt lgkmcnt(0)\n\ts_barrier" ::: "memory")

__device__ __forceinline__ float exp2f_(float x) {
#if __has_builtin(__builtin_amdgcn_exp2f)
  return __builtin_amdgcn_exp2f(x);
#else
  return exp2f(x);
#endif
}
__device__ __forceinline__ float log2f_(float x) {
#if __has_builtin(__builtin_amdgcn_logf)
  return __builtin_amdgcn_logf(x);
#else
  return log2f(x);
#endif
}
__device__ __forceinline__ uint32_t pknorm16(float a, float b) {
#if __has_builtin(__builtin_amdgcn_cvt_pknorm_u16)
  typedef unsigned short u2v __attribute__((ext_vector_type(2)));
  union { u2v v; uint32_t u; } cv;
  cv.v = __builtin_amdgcn_cvt_pknorm_u16(a, b);
  return cv.u;
#else
  uint32_t pa = (uint32_t)(a * 65535.0f + 0.5f);
  uint32_t pb = (uint32_t)(b * 65535.0f + 0.5f);
  return pa | (pb << 16);
#endif
}
__device__ __forceinline__ float bpermf(int addr, float v) {
  return __int_as_float(__builtin_amdgcn_ds_bpermute(addr, __float_as_int(v)));
}
__device__ __forceinline__ uint32_t bpermu(int addr, uint32_t v) {
  return (uint32_t)__builtin_amdgcn_ds_bpermute(addr, (int)v);
}

// offset of diagonal d (d in [2,1024]); lo(d)=max(1,d-512)
__device__ __forceinline__ int offd(int d) {
  return (d <= 513) ? (((d - 2) * (d - 1)) >> 1)
                    : (NCELL - (((1025 - d) * (1026 - d)) >> 1));
}
__device__ __forceinline__ int dbase(int d) {
  const int lo = (d > 513) ? d - 512 : 1;
  return offd(d) - lo;
}
__device__ __forceinline__ int clampa(int a) {
  return a > (NCELL - 1) ? (NCELL - 1) : a;
}

// forward softmax-LSE cell (base-2 domain)
__device__ __forceinline__ void fcell(float& nv, uint32_t& pk, float dg, float up0,
                                      float lf0, float th, float A2) {
  float up = up0 + A2, lf = lf0 + A2;
  float mx = fmaxf(fmaxf(dg, up), lf);
  float ed = exp2f_(dg - mx), eu = exp2f_(up - mx), el = exp2f_(lf - mx);
  float s = ed + eu + el;
  nv = th + mx + log2f_(s);
  float rs = __builtin_amdgcn_rcpf(s);
  pk = pknorm16(ed * rs, eu * rs);
}

// ---------------------------------------------------------------------------
// K1: T[22][512] = W_embed @ W_proj + b_proj
// ---------------------------------------------------------------------------
__global__ void k_T(const float* __restrict__ We, const float* __restrict__ Wp,
                    const float* __restrict__ bp, float* __restrict__ T) {
  int a = blockIdx.x, c = threadIdx.x;
  __shared__ float e[512];
  e[c] = We[a * 512 + c];
  __syncthreads();
  float acc = bp[c];
#pragma unroll 8
  for (int k = 0; k < 512; ++k) acc = fmaf(e[k], Wp[k * 512 + c], acc);
  T[a * 512 + c] = acc;
}

// ---------------------------------------------------------------------------
// K2: G2 = (T T^T)/ln2 ; u,v gap LUTs
// ---------------------------------------------------------------------------
__global__ void k_G(const float* __restrict__ T, const float* __restrict__ Wg,
                    float* __restrict__ G, float* __restrict__ u, float* __restrict__ v) {
  __shared__ float Ts[22 * 516];
  for (int k = threadIdx.x; k < 22 * 512; k += 512) {
    int a = k >> 9, c = k & 511;
    Ts[a * 516 + c] = T[k];
  }
  __syncthreads();
  for (int idx = threadIdx.x; idx < 528; idx += 512) {
    float s = 0.f;
    if (idx < 484) {
      int a = idx / 22, a2 = idx - 22 * a;
      const float* pa = &Ts[a * 516];
      const float* pb = &Ts[a2 * 516];
      for (int c = 0; c < 512; ++c) s = fmaf(pa[c], pb[c], s);
      G[idx] = s * INVLN2;
    } else if (idx < 506) {
      int a = idx - 484;
      const float* pa = &Ts[a * 516];
      for (int c = 0; c < 512; ++c) s = fmaf(pa[c], Wg[c], s);
      u[a] = s;
    } else {
      int a = idx - 506;
      const float* pa = &Ts[a * 516];
      for (int c = 0; c < 512; ++c) s = fmaf(pa[c], Wg[512 + c], s);
      v[a] = s;
    }
  }
}

// ---------------------------------------------------------------------------
// K3: A2[b]
// ---------------------------------------------------------------------------
__global__ void k_A(const int* __restrict__ x, const int* __restrict__ y,
                    const float* __restrict__ u, const float* __restrict__ v,
                    const float* __restrict__ bg, float* __restrict__ A) {
  int b = blockIdx.x, t = threadIdx.x;
  const int* xb = x + b * 512;
  const int* yb = y + b * 512;
  float s = u[xb[t]] + u[xb[t + 256]] + v[yb[t]] + v[yb[t + 256]];
  for (int o = 32; o > 0; o >>= 1) s += __shfl_down(s, o, 64);
  __shared__ float w[4];
  if ((t & 63) == 0) w[t >> 6] = s;
  __syncthreads();
  if (t == 0) A[b] = ((w[0] + w[1] + w[2] + w[3]) * (1.0f / 512.0f) + bg[0]) * INVLN2;
}

// ---------------------------------------------------------------------------
// K4: register-resident K-diagonal wavefront DP.
//     4 waves x 64 lanes; lane owns rows r1=128w+2l+1, r2=r1+1.
//     Cross-lane via ds_bpermute rotate; cross-wave via redundant halo rows
//     (fwd: lanes 56..63 recompute rows 128w-7..128w; bwd: lanes 0..7
//      recompute rows 128(w+1)+1..+8). One barrier per KD diagonals.
// ---------------------------------------------------------------------------
__global__ __launch_bounds__(256) void k_nw(const int* __restrict__ x, const int* __restrict__ y,
                                            const float* __restrict__ G,
                                            const float* __restrict__ Aarr,
                                            uint32_t* __restrict__ po,
                                            float* __restrict__ ews) {
  const int b = blockIdx.x, tid = threadIdx.x;
  const int wave = tid >> 6, lane = tid & 63;
  __shared__ float Gl[484];
  __shared__ int ysL[512];
  __shared__ float Vc[2][516], Vp[2][516], EcS[2][516], EpS[2][516];

  const int* xb = x + b * 512;
  const int* yb = y + b * 512;
  ysL[tid] = yb[tid];
  ysL[tid + 256] = yb[tid + 256];
  for (int k = tid; k < 484; k += 256) Gl[k] = G[k];
  const float A2 = Aarr[b];

  const int r1 = 128 * wave + 2 * lane + 1, r2 = r1 + 1;
  const int xr1 = xb[r1 - 1] * 22, xr2 = xb[r2 - 1] * 22;
  const int Hrow = 128 * wave - (63 - lane);  // fwd halo row (lanes 56..63 meaningful)
  const int xrH = (Hrow >= 1) ? xb[Hrow - 1] * 22 : 0;
  const int HB = 128 * (wave + 1) + 1 + lane;  // bwd halo row (lanes 0..7 meaningful)
  const int HBc = HB <= 512 ? HB : 512;
  const int rotU = ((lane + 63) & 63) << 2;  // lane l <- l-1 (rotate)
  const int rotD = ((lane + 1) & 63) << 2;   // lane l <- l+1 (rotate)
  po += (size_t)b * NCELL;
  ews += (size_t)b * NCELL;
  __syncthreads();

  // ================= forward =================
  float a1 = NEGF, a2r = NEGF, b1v = NEGF, b2v = NEGF, ha = NEGF, hb = NEGF;
#pragma unroll 1
  for (int iv = 0; iv < 128; ++iv) {
    const int d0 = 1 + KD * iv;  // last completed diagonal
    // batched theta gathers for the interval
    float th1[KD], th2[KD], thh[KD];
#pragma unroll
    for (int m = 0; m < KD; ++m) {
      const int dn = d0 + 1 + m;
      unsigned j1 = (unsigned)(dn - r1 - 1);
      th1[m] = Gl[xr1 + ysL[j1 < 512u ? j1 : 0]];
      unsigned j2 = (unsigned)(dn - r2 - 1);
      th2[m] = Gl[xr2 + ysL[j2 < 512u ? j2 : 0]];
      unsigned jh = (unsigned)(dn - Hrow - 1);
      thh[m] = Gl[xrH + ysL[jh < 512u ? jh : 0]];
    }
#pragma unroll
    for (int m = 0; m < KD; ++m) {
      const int dn = d0 + 1 + m;
      const int base = dbase(dn);
      // rotates (full-exec)
      float sa = (lane == 63) ? ha : a2r;
      float sb = (lane == 63) ? hb : b2v;
      float ra2 = bpermf(rotU, sa);
      float rb2 = bpermf(rotU, sb);
      float rha = bpermf(rotU, ha);
      float rhb = bpermf(rotU, hb);
      if (wave == 0 && lane == 0) rb2 = (dn == 2) ? 0.0f : NEGF;  // V[0,0] corner
      // cells
      float nv1, nv2, nh;
      uint32_t pk1, pk2, pkh;
      fcell(nv1, pk1, rb2, ra2, a1, th1[m], A2);   // (r1): diag,up,left
      fcell(nv2, pk2, b1v, a1, a2r, th2[m], A2);   // (r2)
      fcell(nh, pkh, rhb, rha, ha, thh[m], A2);    // halo row
      const bool v1 = (unsigned)(dn - r1 - 1) < 512u;
      const bool v2 = (unsigned)(dn - r2 - 1) < 512u;
      const bool vh = (unsigned)(dn - Hrow - 1) < 512u;
      nv1 = v1 ? nv1 : NEGF;
      nv2 = v2 ? nv2 : NEGF;
      nh = (Hrow >= 1 && vh) ? nh : NEGF;
      if (v1) po[base + r1] = pk1;
      if (v2) po[base + r2] = pk2;
      // roll state
      b1v = a1; b2v = a2r; a1 = nv1; a2r = nv2; hb = ha; ha = nh;
    }
    // interval exchange (double-buffered)
    const int wb = iv & 1;
    Vc[wb][r1] = a1; Vc[wb][r2] = a2r;
    Vp[wb][r1] = b1v; Vp[wb][r2] = b2v;
    BAR();
    const int Hc = Hrow >= 1 ? Hrow : 1;
    float hva = Vc[wb][Hc], hvb = Vp[wb][Hc];
    ha = (Hrow >= 1) ? hva : NEGF;
    hb = (Hrow >= 1) ? hvb : NEGF;
  }

  // ================= transition =================
  asm volatile("s_waitcnt vmcnt(0)" ::: "memory");
  __threadfence_block();
  __syncthreads();

  // ================= backward =================
  const float inv16 = 1.0f / 65535.0f;
  float e1a = 0.f, e1b = 0.f, e2a = 0.f, e2b = 0.f, hc = 0.f, hd = 0.f;
  if (wave == 3 && lane == 63) {
    e1b = 1.0f;                 // E[1024][512] = E(512,512) = 1
    ews[NCELL - 1] = 1.0f;
  }
#pragma unroll 1
  for (int iv = 0; iv < 128; ++iv) {
    const int t0 = 1023 - KD * iv;  // first step's diagonal
    // batched p prefetch: diag dq[k] = t0+2-k, k=0..KD
    uint32_t q1[KD + 1], q2[KD + 1], qh[KD + 1];
#pragma unroll
    for (int k = 0; k <= KD; ++k) {
      const int d = t0 + 2 - k;
      const int base = dbase(d);
      q1[k] = po[clampa(base + r1)];
      q2[k] = po[clampa(base + r2)];
      qh[k] = po[clampa(base + HBc)];
    }
#pragma unroll
    for (int m = 0; m < KD; ++m) {
      const int t = t0 - m;
      const int base = dbase(t);
      // shuffles (full-exec): E and p from lane l+1 (row r2+1 = its r1), halo patch at lane 63
      float sc = (lane == 0) ? hc : e1a;
      float sd = (lane == 0) ? hd : e2a;
      float rc1 = bpermf(rotD, sc);
      float rd1 = bpermf(rotD, sd);
      uint32_t sQ = (lane == 0) ? qh[m] : q1[m];
      uint32_t sP = (lane == 0) ? qh[m + 1] : q1[m + 1];
      uint32_t rQ = bpermu(rotD, sQ);
      uint32_t rP = bpermu(rotD, sP);
      uint32_t rQh = bpermu(rotD, qh[m]);
      uint32_t rPh = bpermu(rotD, qh[m + 1]);
      float rhc = bpermf(rotD, hc);
      float rhd = bpermf(rotD, hd);
      // ---- cell (r1, j1), j1 = t - r1 ----
      const bool vd1 = (unsigned)(t - r1 - 1) < 512u;  // j1 in [1,512]
      const bool rt1 = (unsigned)(t - r1) < 512u;      // j1+1 <= 512
      float pd1 = (float)(q2[m] & 0xffffu) * inv16;                       // p(r2, j1+1)@t+2
      float pu1 = (float)(q2[m + 1] >> 16) * inv16;                       // p(r2, j1)@t+1
      float pl1 = 1.0f - (float)(q1[m + 1] & 0xffffu) * inv16
                       - (float)(q1[m + 1] >> 16) * inv16;                // p(r1, j1+1)@t+1
      float n1 = e1b * pu1 + (rt1 ? (e2b * pd1 + e1a * pl1) : 0.0f);
      n1 = vd1 ? n1 : 0.0f;
      if (vd1) ews[base + r1] = n1;
      // ---- cell (r2, j2), j2 = t - r2 ----
      const bool vd2 = (unsigned)(t - r2 - 1) < 512u;
      const bool rt2 = (unsigned)(t - r2) < 512u;
      const bool dn2 = r2 < 512;
      float pd2 = (float)(rQ & 0xffffu) * inv16;                          // p(r2+1, j2+1)@t+2
      float pu2 = (float)(rP >> 16) * inv16;                              // p(r2+1, j2)@t+1
      float pl2 = 1.0f - (float)(q2[m + 1] & 0xffffu) * inv16
                       - (float)(q2[m + 1] >> 16) * inv16;                // p(r2, j2+1)@t+1
      float n2 = ((dn2 && rt2) ? rd1 * pd2 : 0.0f) + (dn2 ? rc1 * pu2 : 0.0f)
               + (rt2 ? e1b * pl2 : 0.0f);
      n2 = vd2 ? n2 : 0.0f;
      if (vd2) ews[base + r2] = n2;
      // ---- halo cell (HB, jh) ----
      const bool vdh = (unsigned)(t - HB - 1) < 512u;
      const bool rth = (unsigned)(t - HB) < 512u;
      const bool dnh = HB < 512;
      float pdh = (float)(rQh & 0xffffu) * inv16;
      float puh = (float)(rPh >> 16) * inv16;
      float plh = 1.0f - (float)(qh[m + 1] & 0xffffu) * inv16
                       - (float)(qh[m + 1] >> 16) * inv16;
      float nh = ((dnh && rth) ? rhd * pdh : 0.0f) + (dnh ? rhc * puh : 0.0f)
               + (rth ? hc * plh : 0.0f);
      nh = (HB <= 512 && vdh) ? nh : 0.0f;
      // roll
      e2a = e1a; e2b = e1b; e1a = n1; e1b = n2; hd = hc; hc = nh;
    }
    // interval exchange
    const int wb = iv & 1;
    EcS[wb][r1] = e1a; EcS[wb][r2] = e1b;
    EpS[wb][r1] = e2a; EpS[wb][r2] = e2b;
    BAR();
    float hea = EcS[wb][HBc], heb = EpS[wb][HBc];
    hc = (HB <= 512) ? hea : 0.0f;
    hd = (HB <= 512) ? heb : 0.0f;
  }
}

// ---------------------------------------------------------------------------
// K5: transpose diag-major E (ws) -> row-major out. 64x64 cell tiles.
// ---------------------------------------------------------------------------
__global__ __launch_bounds__(256) void k_tr(const float* __restrict__ ews, float* __restrict__ out) {
  const int blk = blockIdx.x;
  const int b = blk >> 6, ti = (blk >> 3) & 7, tj = blk & 7;
  const float* src = ews + (size_t)b * NCELL;
  float* dst = out + (size_t)b * NCELL;
  __shared__ float tile[64][68];
  const int i0 = ti * 64, j0 = tj * 64;
  const int t = threadIdx.x;
  const int sub = t >> 6, lane = t & 63;
  for (int k = sub; k < 127; k += 4) {
    const int d = i0 + j0 + 2 + k;
    const int ilo_t = max(i0 + 1, d - (j0 + 64));
    const int ihi_t = min(i0 + 64, d - (j0 + 1));
    const int i = ilo_t + lane;
    if (i <= ihi_t) {
      const int lo = (d > 513) ? d - 512 : 1;
      tile[i - 1 - i0][d - i - 1 - j0] = src[offd(d) - lo + i];
    }
  }
  __syncthreads();
  const int r = t >> 2, q = (t & 3) * 16;
  float4* drow = (float4*)&dst[(size_t)(i0 + r) * 512 + j0 + q];
  const float* srow = &tile[r][q];
  drow[0] = *(const float4*)&srow[0];
  drow[1] = *(const float4*)&srow[4];
  drow[2] = *(const float4*)&srow[8];
  drow[3] = *(const float4*)&srow[12];
}

// ---------------------------------------------------------------------------
extern "C" void kernel_launch(void* const* d_in, const int* in_sizes, int n_in,
                              void* d_out, int out_size, void* d_ws, size_t ws_size,
                              hipStream_t stream) {
  const int* x = (const int*)d_in[0];
  const int* y = (const int*)d_in[1];
  const float* We = (const float*)d_in[2];
  const float* Wp = (const float*)d_in[3];
  const float* bp = (const float*)d_in[4];
  const float* Wg = (const float*)d_in[5];
  const float* bg = (const float*)d_in[6];
  float* out = (float*)d_out;

  float* ws = (float*)d_ws;
  float* T = ws;              // 22*512 floats
  float* G = ws + 11264;      // 484
  float* u = G + 484;         // 22
  float* v = u + 22;          // 22
  float* A = v + 22;          // 16
  float* ews = (float*)((char*)d_ws + (1 << 20));  // 16 MiB diag-major E

  k_T<<<22, 512, 0, stream>>>(We, Wp, bp, T);
  k_G<<<1, 512, 0, stream>>>(T, Wg, G, u, v);
  k_A<<<16, 256, 0, stream>>>(x, y, u, v, bg, A);
  k_nw<<<16, 256, 0, stream>>>(x, y, G, A, (uint32_t*)d_out, ews);
  k_tr<<<16 * 64, 256, 0, stream>>>(ews, out);
}